// Round 1
// baseline (263.821 us; speedup 1.0000x reference)
//
#include <hip/hip_runtime.h>

// ---------------------------------------------------------------------------
// MaskedSelfAttention, S=8192, D=256, multiplicative mask before softmax.
//   q = query@Wq^T+bq ; k = key@Wk^T+bk ; v = value@Wv^T+bv
//   h = softmax(q@k^T * mask * (1/16)) @ v ; out = h@Wo^T + bo
// Strategy: bf16 MFMA everywhere, f32 accum. No max-tracking (logits bounded
// ~|3|): accumulate sum(exp) and sum(exp*v) directly, normalize in combine.
// ---------------------------------------------------------------------------

#define S 8192
#define NSPLIT 4
#define BM 64
#define BN 32
#define KSPLIT_LEN (S / NSPLIT)   // 2048
#define NTILES (KSPLIT_LEN / BN)  // 64

typedef unsigned short ushort_t;
typedef __attribute__((ext_vector_type(8))) __bf16 bf16x8;
typedef __attribute__((ext_vector_type(4))) float f32x4;
typedef __attribute__((ext_vector_type(4))) ushort_t ushort4_t;
typedef __attribute__((ext_vector_type(8))) ushort_t ushort8_t;

typedef const __attribute__((address_space(1))) unsigned int* gas_u32;
typedef __attribute__((address_space(3))) unsigned int* las_u32;

__device__ __forceinline__ ushort_t f2bf(float f) {
  unsigned u = __builtin_bit_cast(unsigned, f);
  u += 0x7FFFu + ((u >> 16) & 1u);
  return (ushort_t)(u >> 16);
}

__device__ __forceinline__ bf16x8 pack8(f32x4 a, f32x4 b) {
  ushort8_t u;
  u[0] = f2bf(a[0]); u[1] = f2bf(a[1]); u[2] = f2bf(a[2]); u[3] = f2bf(a[3]);
  u[4] = f2bf(b[0]); u[5] = f2bf(b[1]); u[6] = f2bf(b[2]); u[7] = f2bf(b[3]);
  return __builtin_bit_cast(bf16x8, u);
}

// ---------------------------------------------------------------------------
// Projection: OUT = IN @ W^T + b.  IN [8192,256], W [256,256] row-major.
// IN_BF16: 0 = f32 input, 1 = bf16(ushort) input.
// OUT_MODE: 0 = bf16 row-major [8192,256]; 1 = bf16 transposed [256,8192];
//           2 = f32 row-major (final output).
// Block 256 threads (4 waves, 16 rows each), tile 64x64, grid (128,4).
// ---------------------------------------------------------------------------
template <int IN_BF16, int OUT_MODE>
__global__ __launch_bounds__(256) void proj_kernel(const void* __restrict__ inp,
                                                   const float* __restrict__ W,
                                                   const float* __restrict__ bias,
                                                   void* __restrict__ outp) {
  const int tid = threadIdx.x;
  const int lane = tid & 63;
  const int w = tid >> 6;
  const int lr = lane & 15, lg = lane >> 4;
  const int row0 = blockIdx.x * 64 + w * 16;
  const int col0 = blockIdx.y * 64;

  f32x4 acc[4] = {};
  const int arow = row0 + lr;
  const int kb = lg * 8;

#pragma unroll
  for (int ks = 0; ks < 8; ++ks) {
    bf16x8 a;
    if (IN_BF16) {
      a = *(const bf16x8*)((const ushort_t*)inp + (size_t)arow * 256 + ks * 32 + kb);
    } else {
      const float* ap = (const float*)inp + (size_t)arow * 256 + ks * 32 + kb;
      f32x4 a0 = *(const f32x4*)ap;
      f32x4 a1 = *(const f32x4*)(ap + 4);
      a = pack8(a0, a1);
    }
#pragma unroll
    for (int n = 0; n < 4; ++n) {
      const float* bp = W + (size_t)(col0 + 16 * n + lr) * 256 + ks * 32 + kb;
      f32x4 b0 = *(const f32x4*)bp;
      f32x4 b1 = *(const f32x4*)(bp + 4);
      bf16x8 bb = pack8(b0, b1);
      acc[n] = __builtin_amdgcn_mfma_f32_16x16x32_bf16(a, bb, acc[n], 0, 0, 0);
    }
  }

#pragma unroll
  for (int n = 0; n < 4; ++n) {
    const int col = col0 + 16 * n + lr;
    const float bv = bias[col];
    const int rbase = row0 + lg * 4;
    if (OUT_MODE == 0) {
      ushort_t* o = (ushort_t*)outp;
#pragma unroll
      for (int r = 0; r < 4; ++r)
        o[(size_t)(rbase + r) * 256 + col] = f2bf(acc[n][r] + bv);
    } else if (OUT_MODE == 1) {
      ushort4_t pk;
#pragma unroll
      for (int r = 0; r < 4; ++r) pk[r] = f2bf(acc[n][r] + bv);
      *(ushort4_t*)((ushort_t*)outp + (size_t)col * S + rbase) = pk;
    } else {
      float* o = (float*)outp;
#pragma unroll
      for (int r = 0; r < 4; ++r)
        o[(size_t)(rbase + r) * 256 + col] = acc[n][r] + bv;
    }
  }
}

// ---------------------------------------------------------------------------
// Flash attention core (no max-tracking). Grid (128, NSPLIT), block 256.
// Each block: 64 q-rows (wave w owns rows w*16..w*16+15, Q in registers),
// iterates 64 kv-tiles of 32 keys within its split. K-tile [32][256] and
// Vt-tile [256][32] staged to LDS via global_load_lds with XOR chunk swizzle
// (pre-swizzled on the global source address; LDS dest stays linear).
// ---------------------------------------------------------------------------
__global__ __launch_bounds__(256) void flash_kernel(
    const ushort_t* __restrict__ qb, const ushort_t* __restrict__ kbm,
    const ushort_t* __restrict__ vtb, const float* __restrict__ mask,
    float* __restrict__ Opart, float* __restrict__ lpart) {
  __shared__ __align__(16) ushort_t kt[BN * 256];   // 16 KB
  __shared__ __align__(16) ushort_t vt[256 * BN];   // 16 KB
  __shared__ __align__(16) ushort_t pb[4][16 * BN]; // 4 KB, per-wave private

  const int tid = threadIdx.x;
  const int lane = tid & 63;
  const int w = tid >> 6;
  const int lr = lane & 15, lg = lane >> 4;
  const int split = blockIdx.y;
  const int kvbase = split * KSPLIT_LEN;
  const int qrow0 = blockIdx.x * BM + w * 16;

  // Q fragments: row = lr, k = lg*8 + j (+32*ks)
  bf16x8 qf[8];
#pragma unroll
  for (int ks = 0; ks < 8; ++ks)
    qf[ks] = *(const bf16x8*)(qb + (size_t)(qrow0 + lr) * 256 + ks * 32 + lg * 8);

  // mask row pointers for the 4 accumulator rows this lane owns
  const float* mrow[4];
#pragma unroll
  for (int r = 0; r < 4; ++r)
    mrow[r] = mask + (size_t)(qrow0 + lg * 4 + r) * S + lr;

  f32x4 oacc[16] = {};
  float lsum[4] = {0.f, 0.f, 0.f, 0.f};

  const int pa_off = lr * (BN * 2) + lg * 16;      // P A-frag byte offset
  const int vt_swz = ((lg ^ (lane & 3)) << 4);     // Vt read swizzle (const/lane)
  ushort_t* pbw = &pb[w][0];

#pragma unroll 1
  for (int t = 0; t < NTILES; ++t) {
    const int kv0 = kvbase + t * BN;

    // stage K-tile: 32 rows x 512B, 32 chunks/row, chunk c stored at z=c^(r&7)
#pragma unroll
    for (int it = 0; it < 4; ++it) {
      int chunk = it * 256 + (w << 6) + lane;
      int r = chunk >> 5;
      int c = (chunk & 31) ^ (r & 7);
      const ushort_t* src = kbm + (size_t)(kv0 + r) * 256 + c * 8;
      __builtin_amdgcn_global_load_lds((gas_u32)src,
                                       (las_u32)(kt + it * 2048 + w * 512), 16, 0, 0);
    }
    // stage Vt-tile: 256 rows x 64B, 4 chunks/row, chunk c stored at z=c^(r&3)
#pragma unroll
    for (int it = 0; it < 4; ++it) {
      int chunk = it * 256 + (w << 6) + lane;
      int r = chunk >> 2;
      int c = (chunk & 3) ^ (r & 3);
      const ushort_t* src = vtb + (size_t)r * S + kv0 + c * 8;
      __builtin_amdgcn_global_load_lds((gas_u32)src,
                                       (las_u32)(vt + it * 2048 + w * 512), 16, 0, 0);
    }
    __syncthreads();

    // ---- QK^T: S_tile[16 rows][32 keys] per wave ----
    f32x4 sacc[2] = {};
#pragma unroll
    for (int ks = 0; ks < 8; ++ks) {
#pragma unroll
      for (int n = 0; n < 2; ++n) {
        int addr = ((16 * n + lr) << 9) + ((((ks << 2) + lg) ^ (lane & 7)) << 4);
        bf16x8 bk = *(const bf16x8*)((const char*)kt + addr);
        sacc[n] = __builtin_amdgcn_mfma_f32_16x16x32_bf16(qf[ks], bk, sacc[n], 0, 0, 0);
      }
    }

    // ---- mask * scale, exp2, accumulate row sums, stash P as bf16 ----
    // p = exp(s*mask*SCALE) = exp2(s * mask * SCALE*log2(e))
#pragma unroll
    for (int n = 0; n < 2; ++n) {
#pragma unroll
      for (int r = 0; r < 4; ++r) {
        float mv = __builtin_nontemporal_load(mrow[r] + kv0 + 16 * n);
        float p = exp2f(sacc[n][r] * (mv * 0.09016844005556021f));
        lsum[r] += p;
        pbw[(lg * 4 + r) * BN + 16 * n + lr] = f2bf(p);
      }
    }

    // ---- PV: O[16][256] += P[16][32] @ V[32][256] ----
    bf16x8 pa = *(const bf16x8*)((const char*)pbw + pa_off);
#pragma unroll
    for (int nd = 0; nd < 16; ++nd) {
      bf16x8 bv = *(const bf16x8*)((const char*)vt + nd * 1024 + lr * 64 + vt_swz);
      oacc[nd] = __builtin_amdgcn_mfma_f32_16x16x32_bf16(pa, bv, oacc[nd], 0, 0, 0);
    }
    __syncthreads();  // protect kt/vt before next stage
  }

  // ---- epilogue: row sums + unnormalized O partials ----
#pragma unroll
  for (int r = 0; r < 4; ++r) {
    float v = lsum[r];
    v += __shfl_xor(v, 1);
    v += __shfl_xor(v, 2);
    v += __shfl_xor(v, 4);
    v += __shfl_xor(v, 8);
    lsum[r] = v;
  }
  const int absrow0 = qrow0 + lg * 4;
  if (lr == 0) {
#pragma unroll
    for (int r = 0; r < 4; ++r)
      lpart[(size_t)split * S + absrow0 + r] = lsum[r];
  }
#pragma unroll
  for (int r = 0; r < 4; ++r) {
    float* orow = Opart + ((size_t)split * S + absrow0 + r) * 256 + lr;
#pragma unroll
    for (int nd = 0; nd < 16; ++nd) orow[nd * 16] = oacc[nd][r];
  }
}

// ---------------------------------------------------------------------------
// Combine partials: h[row][d] = sum_s O_s[row][d] / sum_s l_s[row] -> bf16
// ---------------------------------------------------------------------------
__global__ __launch_bounds__(256) void combine_kernel(const float* __restrict__ Opart,
                                                      const float* __restrict__ lpart,
                                                      ushort_t* __restrict__ hb) {
  const int row = blockIdx.x;
  const int d = threadIdx.x;
  float L = 0.f, acc = 0.f;
#pragma unroll
  for (int s2 = 0; s2 < NSPLIT; ++s2) {
    L += lpart[(size_t)s2 * S + row];
    acc += Opart[((size_t)s2 * S + row) * 256 + d];
  }
  hb[(size_t)row * 256 + d] = f2bf(acc / L);
}

// ---------------------------------------------------------------------------
extern "C" void kernel_launch(void* const* d_in, const int* in_sizes, int n_in,
                              void* d_out, int out_size, void* d_ws, size_t ws_size,
                              hipStream_t stream) {
  const float* query = (const float*)d_in[0];
  const float* key   = (const float*)d_in[1];
  const float* value = (const float*)d_in[2];
  const float* mask  = (const float*)d_in[3];
  const float* Wq = (const float*)d_in[4];
  const float* bq = (const float*)d_in[5];
  const float* Wk = (const float*)d_in[6];
  const float* bk = (const float*)d_in[7];
  const float* Wv = (const float*)d_in[8];
  const float* bv = (const float*)d_in[9];
  const float* Wo = (const float*)d_in[10];
  const float* bo = (const float*)d_in[11];

  char* ws = (char*)d_ws;
  ushort_t* qb  = (ushort_t*)(ws);                        // 4 MB bf16 [8192,256]
  ushort_t* kb  = (ushort_t*)(ws + ((size_t)4  << 20));   // 4 MB bf16 [8192,256]
  ushort_t* vtb = (ushort_t*)(ws + ((size_t)8  << 20));   // 4 MB bf16 [256,8192]
  ushort_t* hb  = (ushort_t*)(ws + ((size_t)12 << 20));   // 4 MB bf16 [8192,256]
  float* Opart  = (float*)(ws + ((size_t)16 << 20));      // 32 MB f32 [4,8192,256]
  float* lpart  = (float*)(ws + ((size_t)48 << 20));      // 128 KB f32 [4,8192]

  dim3 pgrid(S / 64, 4);
  proj_kernel<0, 0><<<pgrid, 256, 0, stream>>>(query, Wq, bq, qb);
  proj_kernel<0, 0><<<pgrid, 256, 0, stream>>>(key, Wk, bk, kb);
  proj_kernel<0, 1><<<pgrid, 256, 0, stream>>>(value, Wv, bv, vtb);

  flash_kernel<<<dim3(S / BM, NSPLIT), 256, 0, stream>>>(qb, kb, vtb, mask, Opart, lpart);

  combine_kernel<<<S, 256, 0, stream>>>(Opart, lpart, hb);

  proj_kernel<1, 2><<<pgrid, 256, 0, stream>>>(hb, Wo, bo, (float*)d_out);
}

// Round 2
// 225.652 us; speedup vs baseline: 1.1692x; 1.1692x over previous
//
#include <hip/hip_runtime.h>

// ---------------------------------------------------------------------------
// MaskedSelfAttention, S=8192, D=256, multiplicative mask before softmax.
//   q = query@Wq^T+bq ; k = key@Wk^T+bk ; v = value@Wv^T+bv
//   h = softmax(q@k^T * mask * (1/16)) @ v ; out = h@Wo^T + bo
// bf16 MFMA, f32 accum, no max-tracking (logits bounded ~|3|).
// Round 2: double-buffered K/V staging, mask register prefetch, prebuilt
// bf16 weights, coalesced V-transpose store.
// ---------------------------------------------------------------------------

#define S 8192
#define NSPLIT 4
#define BM 64
#define BN 32
#define KSPLIT_LEN (S / NSPLIT)   // 2048
#define NTILES (KSPLIT_LEN / BN)  // 64

typedef unsigned short ushort_t;
typedef __attribute__((ext_vector_type(8))) __bf16 bf16x8;
typedef __attribute__((ext_vector_type(4))) float f32x4;
typedef __attribute__((ext_vector_type(4))) ushort_t ushort4_t;
typedef __attribute__((ext_vector_type(8))) ushort_t ushort8_t;

typedef const __attribute__((address_space(1))) unsigned int* gas_u32;
typedef __attribute__((address_space(3))) unsigned int* las_u32;

__device__ __forceinline__ ushort_t f2bf(float f) {
  unsigned u = __builtin_bit_cast(unsigned, f);
  u += 0x7FFFu + ((u >> 16) & 1u);
  return (ushort_t)(u >> 16);
}

__device__ __forceinline__ bf16x8 pack8(f32x4 a, f32x4 b) {
  ushort8_t u;
  u[0] = f2bf(a[0]); u[1] = f2bf(a[1]); u[2] = f2bf(a[2]); u[3] = f2bf(a[3]);
  u[4] = f2bf(b[0]); u[5] = f2bf(b[1]); u[6] = f2bf(b[2]); u[7] = f2bf(b[3]);
  return __builtin_bit_cast(bf16x8, u);
}

// ---------------------------------------------------------------------------
// Convert 4 weight matrices f32 -> bf16. grid (64,4), block 256, 4 elem/thread.
// ---------------------------------------------------------------------------
__global__ __launch_bounds__(256) void wconv_kernel(
    const float* __restrict__ w0, const float* __restrict__ w1,
    const float* __restrict__ w2, const float* __restrict__ w3,
    ushort_t* __restrict__ o0, ushort_t* __restrict__ o1,
    ushort_t* __restrict__ o2, ushort_t* __restrict__ o3) {
  const int m = blockIdx.y;
  const float* w = (m == 0) ? w0 : (m == 1) ? w1 : (m == 2) ? w2 : w3;
  ushort_t* o = (m == 0) ? o0 : (m == 1) ? o1 : (m == 2) ? o2 : o3;
  const int idx = (blockIdx.x * 256 + threadIdx.x) * 4;
  f32x4 v = *(const f32x4*)(w + idx);
  ushort4_t p;
  p[0] = f2bf(v[0]); p[1] = f2bf(v[1]); p[2] = f2bf(v[2]); p[3] = f2bf(v[3]);
  *(ushort4_t*)(o + idx) = p;
}

// ---------------------------------------------------------------------------
// Projection: OUT = IN @ W^T + b.  IN [8192,256], Wb [256,256] bf16 row-major.
// IN_BF16: 0 = f32 input, 1 = bf16 input.
// OUT_MODE: 0 = bf16 row-major; 1 = bf16 transposed [256,8192] (LDS-coalesced);
//           2 = f32 row-major.
// Block 256 (4 waves x 16 rows), tile 64x64, grid (128,4).
// ---------------------------------------------------------------------------
template <int IN_BF16, int OUT_MODE>
__global__ __launch_bounds__(256) void proj_kernel(const void* __restrict__ inp,
                                                   const ushort_t* __restrict__ Wb,
                                                   const float* __restrict__ bias,
                                                   void* __restrict__ outp) {
  const int tid = threadIdx.x;
  const int lane = tid & 63;
  const int w = tid >> 6;
  const int lr = lane & 15, lg = lane >> 4;
  const int brow0 = blockIdx.x * 64;
  const int row0 = brow0 + w * 16;
  const int col0 = blockIdx.y * 64;

  f32x4 acc[4] = {};
  const int arow = row0 + lr;
  const int kb = lg * 8;

  // A fragments for all 8 k-steps
  bf16x8 af[8];
#pragma unroll
  for (int ks = 0; ks < 8; ++ks) {
    if (IN_BF16) {
      af[ks] = *(const bf16x8*)((const ushort_t*)inp + (size_t)arow * 256 + ks * 32 + kb);
    } else {
      const float* ap = (const float*)inp + (size_t)arow * 256 + ks * 32 + kb;
      af[ks] = pack8(*(const f32x4*)ap, *(const f32x4*)(ap + 4));
    }
  }

#pragma unroll
  for (int ks = 0; ks < 8; ++ks) {
#pragma unroll
    for (int n = 0; n < 4; ++n) {
      bf16x8 bb = *(const bf16x8*)(Wb + (size_t)(col0 + 16 * n + lr) * 256 + ks * 32 + kb);
      acc[n] = __builtin_amdgcn_mfma_f32_16x16x32_bf16(af[ks], bb, acc[n], 0, 0, 0);
    }
  }

  if constexpr (OUT_MODE == 1) {
    // transpose through LDS, then coalesced 128B-row stores
    __shared__ __align__(16) ushort_t tb[64 * 68];  // [col_local][row_local], pad 68
#pragma unroll
    for (int n = 0; n < 4; ++n) {
      const int col = col0 + 16 * n + lr;
      const float bv = bias[col];
      const int cl = 16 * n + lr;
      const int rowl = w * 16 + lg * 4;
      ushort4_t pk;
#pragma unroll
      for (int r = 0; r < 4; ++r) pk[r] = f2bf(acc[n][r] + bv);
      *(ushort4_t*)&tb[cl * 68 + rowl] = pk;
    }
    __syncthreads();
    ushort_t* o = (ushort_t*)outp;
#pragma unroll
    for (int i = 0; i < 4; ++i) {
      int chunk = i * 256 + tid;       // 1024 chunks of 8B: 64 cols x 16 chunks
      int c = chunk >> 4;              // local col (v row)
      int off = (chunk & 15) * 4;      // element offset within 64-row span
      ushort4_t v0 = *(const ushort4_t*)&tb[c * 68 + off];
      *(ushort4_t*)(o + (size_t)(col0 + c) * S + brow0 + off) = v0;
    }
  } else {
#pragma unroll
    for (int n = 0; n < 4; ++n) {
      const int col = col0 + 16 * n + lr;
      const float bv = bias[col];
      const int rbase = row0 + lg * 4;
      if (OUT_MODE == 0) {
        ushort_t* o = (ushort_t*)outp;
#pragma unroll
        for (int r = 0; r < 4; ++r)
          o[(size_t)(rbase + r) * 256 + col] = f2bf(acc[n][r] + bv);
      } else {
        float* o = (float*)outp;
#pragma unroll
        for (int r = 0; r < 4; ++r)
          o[(size_t)(rbase + r) * 256 + col] = acc[n][r] + bv;
      }
    }
  }
}

// ---------------------------------------------------------------------------
// Flash attention core. Grid (128, NSPLIT), block 256 (4 waves x 16 q-rows).
// Double-buffered K/V LDS staging (stage t+1 during compute of t), mask
// prefetched one tile ahead into registers.
// ---------------------------------------------------------------------------
__global__ __launch_bounds__(256) void flash_kernel(
    const ushort_t* __restrict__ qb, const ushort_t* __restrict__ kbm,
    const ushort_t* __restrict__ vtb, const float* __restrict__ mask,
    float* __restrict__ Opart, float* __restrict__ lpart) {
  __shared__ __align__(16) ushort_t kt[2 * BN * 256];   // 2 x 16 KB
  __shared__ __align__(16) ushort_t vt[2 * 256 * BN];   // 2 x 16 KB
  __shared__ __align__(16) ushort_t pb[4][16 * BN];     // 4 KB, per-wave

  const int tid = threadIdx.x;
  const int lane = tid & 63;
  const int w = tid >> 6;
  const int lr = lane & 15, lg = lane >> 4;
  const int split = blockIdx.y;
  const int kvbase = split * KSPLIT_LEN;
  const int qrow0 = blockIdx.x * BM + w * 16;

  // Q fragments: row = lr, k = lg*8 + j (+32*ks)
  bf16x8 qf[8];
#pragma unroll
  for (int ks = 0; ks < 8; ++ks)
    qf[ks] = *(const bf16x8*)(qb + (size_t)(qrow0 + lr) * 256 + ks * 32 + lg * 8);

  const float* mrow[4];
#pragma unroll
  for (int r = 0; r < 4; ++r)
    mrow[r] = mask + (size_t)(qrow0 + lg * 4 + r) * S + lr;

  f32x4 oacc[16] = {};
  float lsum[4] = {0.f, 0.f, 0.f, 0.f};

  const int pa_off = lr * (BN * 2) + lg * 16;      // P A-frag byte offset
  const int vt_swz = ((lg ^ (lane & 3)) << 4);
  ushort_t* pbw = &pb[w][0];

  auto stage = [&](int b, int kv0) {
#pragma unroll
    for (int it = 0; it < 4; ++it) {
      int chunk = it * 256 + (w << 6) + lane;
      int r = chunk >> 5;
      int c = (chunk & 31) ^ (r & 7);
      const ushort_t* src = kbm + (size_t)(kv0 + r) * 256 + c * 8;
      __builtin_amdgcn_global_load_lds((gas_u32)src,
                                       (las_u32)(kt + b * 8192 + it * 2048 + w * 512), 16, 0, 0);
    }
#pragma unroll
    for (int it = 0; it < 4; ++it) {
      int chunk = it * 256 + (w << 6) + lane;
      int r = chunk >> 2;
      int c = (chunk & 3) ^ (r & 3);
      const ushort_t* src = vtb + (size_t)r * S + kv0 + c * 8;
      __builtin_amdgcn_global_load_lds((gas_u32)src,
                                       (las_u32)(vt + b * 8192 + it * 2048 + w * 512), 16, 0, 0);
    }
  };

  // prologue: stage tile 0, prefetch mask tile 0
  stage(0, kvbase);
  float mcur[8];
#pragma unroll
  for (int n = 0; n < 2; ++n)
#pragma unroll
    for (int r = 0; r < 4; ++r)
      mcur[n * 4 + r] = __builtin_nontemporal_load(mrow[r] + kvbase + 16 * n);
  __syncthreads();

  for (int t = 0; t < NTILES; ++t) {
    const int cur = t & 1;
    const int tn = (t + 1 < NTILES) ? (t + 1) : t;   // clamped next tile
    const int kvn = kvbase + tn * BN;

    // issue next-tile staging + mask prefetch FIRST (hidden under compute)
    stage(cur ^ 1, kvn);
    float mnext[8];
#pragma unroll
    for (int n = 0; n < 2; ++n)
#pragma unroll
      for (int r = 0; r < 4; ++r)
        mnext[n * 4 + r] = __builtin_nontemporal_load(mrow[r] + kvn + 16 * n);

    // ---- QK^T from buffer `cur` ----
    const char* ktc = (const char*)kt + cur * 16384;
    f32x4 sacc[2] = {};
#pragma unroll
    for (int ks = 0; ks < 8; ++ks) {
#pragma unroll
      for (int n = 0; n < 2; ++n) {
        int addr = ((16 * n + lr) << 9) + ((((ks << 2) + lg) ^ (lane & 7)) << 4);
        bf16x8 bk = *(const bf16x8*)(ktc + addr);
        sacc[n] = __builtin_amdgcn_mfma_f32_16x16x32_bf16(qf[ks], bk, sacc[n], 0, 0, 0);
      }
    }

    // ---- softmax numerator: p = exp2(s * mask * SCALE*log2e) ----
#pragma unroll
    for (int n = 0; n < 2; ++n) {
#pragma unroll
      for (int r = 0; r < 4; ++r) {
        float p = __builtin_amdgcn_exp2f(sacc[n][r] * (mcur[n * 4 + r] * 0.09016844005556021f));
        lsum[r] += p;
        pbw[(lg * 4 + r) * BN + 16 * n + lr] = f2bf(p);
      }
    }

    // ---- PV from buffer `cur` ----
    const char* vtc = (const char*)vt + cur * 16384;
    bf16x8 pa = *(const bf16x8*)((const char*)pbw + pa_off);
#pragma unroll
    for (int nd = 0; nd < 16; ++nd) {
      bf16x8 bv = *(const bf16x8*)(vtc + nd * 1024 + lr * 64 + vt_swz);
      oacc[nd] = __builtin_amdgcn_mfma_f32_16x16x32_bf16(pa, bv, oacc[nd], 0, 0, 0);
    }

#pragma unroll
    for (int i = 0; i < 8; ++i) mcur[i] = mnext[i];
    __syncthreads();   // next-tile staging complete; everyone done with `cur`
  }

  // ---- epilogue ----
#pragma unroll
  for (int r = 0; r < 4; ++r) {
    float v = lsum[r];
    v += __shfl_xor(v, 1);
    v += __shfl_xor(v, 2);
    v += __shfl_xor(v, 4);
    v += __shfl_xor(v, 8);
    lsum[r] = v;
  }
  const int absrow0 = qrow0 + lg * 4;
  if (lr == 0) {
#pragma unroll
    for (int r = 0; r < 4; ++r)
      lpart[(size_t)split * S + absrow0 + r] = lsum[r];
  }
#pragma unroll
  for (int r = 0; r < 4; ++r) {
    float* orow = Opart + ((size_t)split * S + absrow0 + r) * 256 + lr;
#pragma unroll
    for (int nd = 0; nd < 16; ++nd) orow[nd * 16] = oacc[nd][r];
  }
}

// ---------------------------------------------------------------------------
// Combine partials: h[row][d] = sum_s O_s[row][d] / sum_s l_s[row] -> bf16
// ---------------------------------------------------------------------------
__global__ __launch_bounds__(256) void combine_kernel(const float* __restrict__ Opart,
                                                      const float* __restrict__ lpart,
                                                      ushort_t* __restrict__ hb) {
  const int row = blockIdx.x;
  const int d = threadIdx.x;
  float L = 0.f, acc = 0.f;
#pragma unroll
  for (int s2 = 0; s2 < NSPLIT; ++s2) {
    L += lpart[(size_t)s2 * S + row];
    acc += Opart[((size_t)s2 * S + row) * 256 + d];
  }
  hb[(size_t)row * 256 + d] = f2bf(acc / L);
}

// ---------------------------------------------------------------------------
extern "C" void kernel_launch(void* const* d_in, const int* in_sizes, int n_in,
                              void* d_out, int out_size, void* d_ws, size_t ws_size,
                              hipStream_t stream) {
  const float* query = (const float*)d_in[0];
  const float* key   = (const float*)d_in[1];
  const float* value = (const float*)d_in[2];
  const float* mask  = (const float*)d_in[3];
  const float* Wq = (const float*)d_in[4];
  const float* bq = (const float*)d_in[5];
  const float* Wk = (const float*)d_in[6];
  const float* bk = (const float*)d_in[7];
  const float* Wv = (const float*)d_in[8];
  const float* bv = (const float*)d_in[9];
  const float* Wo = (const float*)d_in[10];
  const float* bo = (const float*)d_in[11];

  char* ws = (char*)d_ws;
  ushort_t* qb  = (ushort_t*)(ws);                        // 4 MB bf16 [8192,256]
  ushort_t* kb  = (ushort_t*)(ws + ((size_t)4  << 20));   // 4 MB bf16 [8192,256]
  ushort_t* vtb = (ushort_t*)(ws + ((size_t)8  << 20));   // 4 MB bf16 [256,8192]
  ushort_t* hb  = (ushort_t*)(ws + ((size_t)12 << 20));   // 4 MB bf16 [8192,256]
  float* Opart  = (float*)(ws + ((size_t)16 << 20));      // 32 MB f32 [4,8192,256]
  float* lpart  = (float*)(ws + ((size_t)48 << 20));      // 128 KB f32 [4,8192]
  ushort_t* Wqb = (ushort_t*)(ws + ((size_t)49 << 20));                 // 128 KB
  ushort_t* Wkb = (ushort_t*)(ws + ((size_t)49 << 20) + (128u << 10));
  ushort_t* Wvb = (ushort_t*)(ws + ((size_t)49 << 20) + (256u << 10));
  ushort_t* Wob = (ushort_t*)(ws + ((size_t)49 << 20) + (384u << 10));

  wconv_kernel<<<dim3(64, 4), 256, 0, stream>>>(Wq, Wk, Wv, Wo, Wqb, Wkb, Wvb, Wob);

  dim3 pgrid(S / 64, 4);
  proj_kernel<0, 0><<<pgrid, 256, 0, stream>>>(query, Wqb, bq, qb);
  proj_kernel<0, 0><<<pgrid, 256, 0, stream>>>(key, Wkb, bk, kb);
  proj_kernel<0, 1><<<pgrid, 256, 0, stream>>>(value, Wvb, bv, vtb);

  flash_kernel<<<dim3(S / BM, NSPLIT), 256, 0, stream>>>(qb, kb, vtb, mask, Opart, lpart);

  combine_kernel<<<S, 256, 0, stream>>>(Opart, lpart, hb);

  proj_kernel<1, 2><<<pgrid, 256, 0, stream>>>(hb, Wob, bo, (float*)d_out);
}

// Round 3
// 225.329 us; speedup vs baseline: 1.1708x; 1.0014x over previous
//
#include <hip/hip_runtime.h>

// ---------------------------------------------------------------------------
// MaskedSelfAttention, S=8192, D=256, multiplicative mask before softmax.
//   q = query@Wq^T+bq ; k = key@Wk^T+bk ; v = value@Wv^T+bv
//   h = softmax(q@k^T * mask * (1/16)) @ v ; out = h@Wo^T + bo
// Round 3: 32 q-rows/wave (halved LDS traffic), swapped-QK^T + permlane
// in-register P (no P LDS stash), counted-vmcnt barriers, fused QKV proj.
// ---------------------------------------------------------------------------

#define S 8192
#define BM 128   // q-rows per block (4 waves x 32)
#define BN 32    // keys per tile

typedef unsigned short ushort_t;
typedef __attribute__((ext_vector_type(8))) __bf16 bf16x8;
typedef __attribute__((ext_vector_type(4))) float f32x4;
typedef __attribute__((ext_vector_type(4))) ushort_t ushort4_t;
typedef __attribute__((ext_vector_type(8))) ushort_t ushort8_t;
typedef __attribute__((ext_vector_type(4))) unsigned uint4_t;

typedef const __attribute__((address_space(1))) unsigned int* gas_u32;
typedef __attribute__((address_space(3))) unsigned int* las_u32;

__device__ __forceinline__ ushort_t f2bf(float f) {
  unsigned u = __builtin_bit_cast(unsigned, f);
  u += 0x7FFFu + ((u >> 16) & 1u);
  return (ushort_t)(u >> 16);
}

__device__ __forceinline__ bf16x8 pack8(f32x4 a, f32x4 b) {
  ushort8_t u;
  u[0] = f2bf(a[0]); u[1] = f2bf(a[1]); u[2] = f2bf(a[2]); u[3] = f2bf(a[3]);
  u[4] = f2bf(b[0]); u[5] = f2bf(b[1]); u[6] = f2bf(b[2]); u[7] = f2bf(b[3]);
  return __builtin_bit_cast(bf16x8, u);
}

__device__ __forceinline__ unsigned cvt_pk_bf16(float lo, float hi) {
  unsigned r;
  asm("v_cvt_pk_bf16_f32 %0, %1, %2" : "=v"(r) : "v"(lo), "v"(hi));
  return r;
}

// ---------------------------------------------------------------------------
// Convert 4 weight matrices f32 -> bf16. grid (64,4), block 256.
// ---------------------------------------------------------------------------
__global__ __launch_bounds__(256) void wconv_kernel(
    const float* __restrict__ w0, const float* __restrict__ w1,
    const float* __restrict__ w2, const float* __restrict__ w3,
    ushort_t* __restrict__ o0, ushort_t* __restrict__ o1,
    ushort_t* __restrict__ o2, ushort_t* __restrict__ o3) {
  const int m = blockIdx.y;
  const float* w = (m == 0) ? w0 : (m == 1) ? w1 : (m == 2) ? w2 : w3;
  ushort_t* o = (m == 0) ? o0 : (m == 1) ? o1 : (m == 2) ? o2 : o3;
  const int idx = (blockIdx.x * 256 + threadIdx.x) * 4;
  f32x4 v = *(const f32x4*)(w + idx);
  ushort4_t p;
  p[0] = f2bf(v[0]); p[1] = f2bf(v[1]); p[2] = f2bf(v[2]); p[3] = f2bf(v[3]);
  *(ushort4_t*)(o + idx) = p;
}

// ---------------------------------------------------------------------------
// Fused QKV projection. grid (128, 4, 3): z selects {q,k,v}. z==2 writes the
// transposed [256,8192] bf16 V^T through an LDS transpose (coalesced stores).
// ---------------------------------------------------------------------------
__global__ __launch_bounds__(256) void qkv_kernel(
    const float* __restrict__ query, const float* __restrict__ key,
    const float* __restrict__ value,
    const ushort_t* __restrict__ Wqb, const ushort_t* __restrict__ Wkb,
    const ushort_t* __restrict__ Wvb,
    const float* __restrict__ bq, const float* __restrict__ bk,
    const float* __restrict__ bv,
    ushort_t* __restrict__ qo, ushort_t* __restrict__ ko,
    ushort_t* __restrict__ vto) {
  __shared__ __align__(16) ushort_t tb[64 * 68];
  const int z = blockIdx.z;
  const float* inp = (z == 0) ? query : (z == 1) ? key : value;
  const ushort_t* Wb = (z == 0) ? Wqb : (z == 1) ? Wkb : Wvb;
  const float* bias = (z == 0) ? bq : (z == 1) ? bk : bv;

  const int tid = threadIdx.x;
  const int lane = tid & 63;
  const int w = tid >> 6;
  const int lr = lane & 15, lg = lane >> 4;
  const int brow0 = blockIdx.x * 64;
  const int row0 = brow0 + w * 16;
  const int col0 = blockIdx.y * 64;

  f32x4 acc[4] = {};
  const int arow = row0 + lr;
  const int kb = lg * 8;

  bf16x8 af[8];
#pragma unroll
  for (int ks = 0; ks < 8; ++ks) {
    const float* ap = inp + (size_t)arow * 256 + ks * 32 + kb;
    af[ks] = pack8(*(const f32x4*)ap, *(const f32x4*)(ap + 4));
  }
#pragma unroll
  for (int ks = 0; ks < 8; ++ks) {
#pragma unroll
    for (int n = 0; n < 4; ++n) {
      bf16x8 bb = *(const bf16x8*)(Wb + (size_t)(col0 + 16 * n + lr) * 256 + ks * 32 + kb);
      acc[n] = __builtin_amdgcn_mfma_f32_16x16x32_bf16(af[ks], bb, acc[n], 0, 0, 0);
    }
  }

  if (z < 2) {
    ushort_t* o = z ? ko : qo;
#pragma unroll
    for (int n = 0; n < 4; ++n) {
      const int col = col0 + 16 * n + lr;
      const float bv_ = bias[col];
      const int rbase = row0 + lg * 4;
#pragma unroll
      for (int r = 0; r < 4; ++r)
        o[(size_t)(rbase + r) * 256 + col] = f2bf(acc[n][r] + bv_);
    }
  } else {
#pragma unroll
    for (int n = 0; n < 4; ++n) {
      const int col = col0 + 16 * n + lr;
      const float bv_ = bias[col];
      const int cl = 16 * n + lr;
      const int rowl = w * 16 + lg * 4;
      ushort4_t pk;
#pragma unroll
      for (int r = 0; r < 4; ++r) pk[r] = f2bf(acc[n][r] + bv_);
      *(ushort4_t*)&tb[cl * 68 + rowl] = pk;
    }
    __syncthreads();
#pragma unroll
    for (int i = 0; i < 4; ++i) {
      int chunk = i * 256 + tid;
      int c = chunk >> 4;
      int off = (chunk & 15) * 4;
      ushort4_t v0 = *(const ushort4_t*)&tb[c * 68 + off];
      *(ushort4_t*)(vto + (size_t)(col0 + c) * S + brow0 + off) = v0;
    }
  }
}

// ---------------------------------------------------------------------------
// Output projection: f32 out = hb(bf16) @ Wo^T + bo. grid (128,4).
// ---------------------------------------------------------------------------
__global__ __launch_bounds__(256) void oproj_kernel(const ushort_t* __restrict__ inp,
                                                    const ushort_t* __restrict__ Wb,
                                                    const float* __restrict__ bias,
                                                    float* __restrict__ outp) {
  const int tid = threadIdx.x;
  const int lane = tid & 63;
  const int w = tid >> 6;
  const int lr = lane & 15, lg = lane >> 4;
  const int row0 = blockIdx.x * 64 + w * 16;
  const int col0 = blockIdx.y * 64;

  f32x4 acc[4] = {};
  const int arow = row0 + lr;
  const int kb = lg * 8;
#pragma unroll
  for (int ks = 0; ks < 8; ++ks) {
    bf16x8 a = *(const bf16x8*)(inp + (size_t)arow * 256 + ks * 32 + kb);
#pragma unroll
    for (int n = 0; n < 4; ++n) {
      bf16x8 bb = *(const bf16x8*)(Wb + (size_t)(col0 + 16 * n + lr) * 256 + ks * 32 + kb);
      acc[n] = __builtin_amdgcn_mfma_f32_16x16x32_bf16(a, bb, acc[n], 0, 0, 0);
    }
  }
#pragma unroll
  for (int n = 0; n < 4; ++n) {
    const int col = col0 + 16 * n + lr;
    const float bv = bias[col];
    const int rbase = row0 + lg * 4;
#pragma unroll
    for (int r = 0; r < 4; ++r)
      outp[(size_t)(rbase + r) * 256 + col] = acc[n][r] + bv;
  }
}

// ---------------------------------------------------------------------------
// Flash attention core. Grid (64, NS), block 256 (4 waves x 32 q-rows).
// Swapped QK^T: sacc = mfma(K_frag, Q_frag) -> P^T, q is lane-local (col=lr).
// P B-frag for PV built in-register via cvt_pk_bf16 + permlane{32,16}_swap.
// Double-buffered K/V staging with counted vmcnt(4) barriers (mask loads
// stay in flight across the barrier).
// ---------------------------------------------------------------------------
template <int NS>
__global__ __launch_bounds__(256, 2) void flash_kernel(
    const ushort_t* __restrict__ qg, const ushort_t* __restrict__ kbm,
    const ushort_t* __restrict__ vtb, const float* __restrict__ mask,
    float* __restrict__ Opart, float* __restrict__ lpart) {
  constexpr int KSPL = S / NS;
  constexpr int NT = KSPL / BN;
  __shared__ __align__(16) ushort_t kt[2][BN * 256];   // 2 x 16 KB
  __shared__ __align__(16) ushort_t vt[2][256 * BN];   // 2 x 16 KB

  const int tid = threadIdx.x;
  const int lane = tid & 63;
  const int w = tid >> 6;
  const int lr = lane & 15, lg = lane >> 4;
  const int split = blockIdx.y;
  const int kvbase = split * KSPL;
  const int qrow0 = blockIdx.x * BM + w * 32;

  // Q fragments (B-operand layout): lane holds Q[q=qb*16+lr][k=ks*32+lg*8+j]
  bf16x8 qf[2][8];
#pragma unroll
  for (int qb = 0; qb < 2; ++qb)
#pragma unroll
    for (int ks = 0; ks < 8; ++ks)
      qf[qb][ks] = *(const bf16x8*)(qg + (size_t)(qrow0 + qb * 16 + lr) * 256 + ks * 32 + lg * 8);

  const float* mrow[2];
#pragma unroll
  for (int qb = 0; qb < 2; ++qb)
    mrow[qb] = mask + (size_t)(qrow0 + qb * 16 + lr) * S + lg * 4;

  f32x4 oacc[2][16] = {};   // O^T: oacc[qb][nd][r] = O[q=qb*16+lr][d=nd*16+lg*4+r]
  float lsum[2] = {0.f, 0.f};
  const int vt_swz = ((lg ^ (lr & 3)) << 4);

  auto stage = [&](int b, int kv0) {
#pragma unroll
    for (int it = 0; it < 4; ++it) {
      int chunk = it * 256 + (w << 6) + lane;
      int r = chunk >> 5;
      int c = (chunk & 31) ^ (r & 7);
      const ushort_t* src = kbm + (size_t)(kv0 + r) * 256 + c * 8;
      __builtin_amdgcn_global_load_lds((gas_u32)src,
                                       (las_u32)(&kt[b][0] + it * 2048 + w * 512), 16, 0, 0);
    }
#pragma unroll
    for (int it = 0; it < 4; ++it) {
      int chunk = it * 256 + (w << 6) + lane;
      int r = chunk >> 2;
      int c = (chunk & 3) ^ (r & 3);
      const ushort_t* src = vtb + (size_t)r * S + kv0 + c * 8;
      __builtin_amdgcn_global_load_lds((gas_u32)src,
                                       (las_u32)(&vt[b][0] + it * 2048 + w * 512), 16, 0, 0);
    }
  };

  // prologue: stage tile 0 (8 loads), then mask tile 0 (4 loads)
  stage(0, kvbase);
  f32x4 mcur[2][2];
#pragma unroll
  for (int qb = 0; qb < 2; ++qb)
#pragma unroll
    for (int kb = 0; kb < 2; ++kb)
      mcur[qb][kb] = __builtin_nontemporal_load((const f32x4*)(mrow[qb] + kvbase + kb * 16));
  asm volatile("s_waitcnt vmcnt(4)" ::: "memory");
  __builtin_amdgcn_s_barrier();
  __builtin_amdgcn_sched_barrier(0);

  for (int t = 0; t < NT; ++t) {
    const int cur = t & 1;
    const int kvn = kvbase + ((t + 1 < NT) ? (t + 1) : t) * BN;

    // staging for t+1 (8 vmem, oldest in queue this iteration)
    stage(cur ^ 1, kvn);

    // ---- QK^T (swapped): sacc[qb][kb] = P^T block [key=kb*16+lg*4+r][q=qb*16+lr]
    f32x4 sacc[2][2] = {};
    __builtin_amdgcn_s_setprio(1);
#pragma unroll
    for (int ks = 0; ks < 8; ++ks) {
#pragma unroll
      for (int kb = 0; kb < 2; ++kb) {
        int addr = ((kb * 16 + lr) << 9) + ((((ks << 2) + lg) ^ (lr & 7)) << 4);
        bf16x8 kf = *(const bf16x8*)((const char*)&kt[cur][0] + addr);
#pragma unroll
        for (int qb = 0; qb < 2; ++qb)
          sacc[qb][kb] = __builtin_amdgcn_mfma_f32_16x16x32_bf16(kf, qf[qb][ks], sacc[qb][kb], 0, 0, 0);
      }
    }
    __builtin_amdgcn_s_setprio(0);

    // ---- softmax numerator + bf16 pack: p = exp2(s * mask * SCALE*log2e)
    unsigned pw[2][2][2];
#pragma unroll
    for (int qb = 0; qb < 2; ++qb) {
      float p[8];
#pragma unroll
      for (int kb = 0; kb < 2; ++kb)
#pragma unroll
        for (int r = 0; r < 4; ++r) {
          float pv = __builtin_amdgcn_exp2f(sacc[qb][kb][r] * (mcur[qb][kb][r] * 0.09016844005556021f));
          p[kb * 4 + r] = pv;
          lsum[qb] += pv;
        }
      pw[qb][0][0] = cvt_pk_bf16(p[0], p[1]);
      pw[qb][0][1] = cvt_pk_bf16(p[2], p[3]);
      pw[qb][1][0] = cvt_pk_bf16(p[4], p[5]);
      pw[qb][1][1] = cvt_pk_bf16(p[6], p[7]);
    }

    // ---- mask prefetch for t+1 (4 vmem, newest; survives the barrier)
#pragma unroll
    for (int qb = 0; qb < 2; ++qb)
#pragma unroll
      for (int kb = 0; kb < 2; ++kb)
        mcur[qb][kb] = __builtin_nontemporal_load((const f32x4*)(mrow[qb] + kvn + kb * 16));

    // ---- permlane redistribution -> PV B-frag (P[k=lg*8+j][q=lr])
    bf16x8 pfrag[2];
#pragma unroll
    for (int qb = 0; qb < 2; ++qb) {
      unsigned a0 = pw[qb][0][0], a1 = pw[qb][0][1];
      unsigned b0 = pw[qb][1][0], b1 = pw[qb][1][1];
      asm("v_permlane32_swap_b32 %0, %1" : "+v"(a0), "+v"(b0));
      asm("v_permlane16_swap_b32 %0, %1" : "+v"(a0), "+v"(b0));
      asm("v_permlane32_swap_b32 %0, %1" : "+v"(a1), "+v"(b1));
      asm("v_permlane16_swap_b32 %0, %1" : "+v"(a1), "+v"(b1));
      uint4_t u = {a0, a1, b0, b1};
      pfrag[qb] = __builtin_bit_cast(bf16x8, u);
    }

    // ---- PV: O^T[d][q] += V^T[d][k] P^T[k][q]
    __builtin_amdgcn_s_setprio(1);
#pragma unroll
    for (int nd = 0; nd < 16; ++nd) {
      bf16x8 va = *(const bf16x8*)((const char*)&vt[cur][0] + nd * 1024 + lr * 64 + vt_swz);
#pragma unroll
      for (int qb = 0; qb < 2; ++qb)
        oacc[qb][nd] = __builtin_amdgcn_mfma_f32_16x16x32_bf16(va, pfrag[qb], oacc[qb][nd], 0, 0, 0);
    }
    __builtin_amdgcn_s_setprio(0);

    // ---- counted-vmcnt barrier: drain 8 staging loads, keep 4 mask loads
    asm volatile("s_waitcnt vmcnt(4)" ::: "memory");
    __builtin_amdgcn_s_barrier();
    __builtin_amdgcn_sched_barrier(0);
  }

  // ---- epilogue ----
#pragma unroll
  for (int qb = 0; qb < 2; ++qb) {
    float v = lsum[qb];
    v += __shfl_xor(v, 16);
    v += __shfl_xor(v, 32);
    if (lane < 16)
      lpart[(size_t)split * S + qrow0 + qb * 16 + lr] = v;
#pragma unroll
    for (int nd = 0; nd < 16; ++nd)
      *(f32x4*)(Opart + ((size_t)split * S + qrow0 + qb * 16 + lr) * 256 + nd * 16 + lg * 4) = oacc[qb][nd];
  }
}

// ---------------------------------------------------------------------------
// Combine partials: h[row][d] = sum_s O_s[row][d] / sum_s l_s[row] -> bf16
// ---------------------------------------------------------------------------
template <int NS>
__global__ __launch_bounds__(256) void combine_kernel(const float* __restrict__ Opart,
                                                      const float* __restrict__ lpart,
                                                      ushort_t* __restrict__ hb) {
  const int row = blockIdx.x;
  const int d = threadIdx.x;
  float L = 0.f, acc = 0.f;
#pragma unroll
  for (int s2 = 0; s2 < NS; ++s2) {
    L += lpart[(size_t)s2 * S + row];
    acc += Opart[((size_t)s2 * S + row) * 256 + d];
  }
  hb[(size_t)row * 256 + d] = f2bf(acc / L);
}

// ---------------------------------------------------------------------------
extern "C" void kernel_launch(void* const* d_in, const int* in_sizes, int n_in,
                              void* d_out, int out_size, void* d_ws, size_t ws_size,
                              hipStream_t stream) {
  const float* query = (const float*)d_in[0];
  const float* key   = (const float*)d_in[1];
  const float* value = (const float*)d_in[2];
  const float* mask  = (const float*)d_in[3];
  const float* Wq = (const float*)d_in[4];
  const float* bq = (const float*)d_in[5];
  const float* Wk = (const float*)d_in[6];
  const float* bk = (const float*)d_in[7];
  const float* Wv = (const float*)d_in[8];
  const float* bv = (const float*)d_in[9];
  const float* Wo = (const float*)d_in[10];
  const float* bo = (const float*)d_in[11];

  char* ws = (char*)d_ws;
  ushort_t* qb  = (ushort_t*)(ws);                        // 4 MB bf16 [8192,256]
  ushort_t* kb  = (ushort_t*)(ws + ((size_t)4  << 20));   // 4 MB bf16 [8192,256]
  ushort_t* vtb = (ushort_t*)(ws + ((size_t)8  << 20));   // 4 MB bf16 [256,8192]
  ushort_t* hb  = (ushort_t*)(ws + ((size_t)12 << 20));   // 4 MB bf16 [8192,256]
  ushort_t* Wqb = (ushort_t*)(ws + ((size_t)16 << 20));                 // 4x128 KB
  ushort_t* Wkb = (ushort_t*)(ws + ((size_t)16 << 20) + (128u << 10));
  ushort_t* Wvb = (ushort_t*)(ws + ((size_t)16 << 20) + (256u << 10));
  ushort_t* Wob = (ushort_t*)(ws + ((size_t)16 << 20) + (384u << 10));
  float* lpart  = (float*)(ws + ((size_t)16 << 20) + (512u << 10));     // <=256 KB
  float* Opart  = (float*)(ws + ((size_t)17 << 20));      // NS x 8 MB

  const bool big = ws_size >= ((size_t)82 << 20);

  wconv_kernel<<<dim3(64, 4), 256, 0, stream>>>(Wq, Wk, Wv, Wo, Wqb, Wkb, Wvb, Wob);

  qkv_kernel<<<dim3(S / 64, 4, 3), 256, 0, stream>>>(query, key, value,
                                                     Wqb, Wkb, Wvb, bq, bk, bv,
                                                     qb, kb, vtb);

  if (big) {
    flash_kernel<8><<<dim3(S / BM, 8), 256, 0, stream>>>(qb, kb, vtb, mask, Opart, lpart);
    combine_kernel<8><<<S, 256, 0, stream>>>(Opart, lpart, hb);
  } else {
    flash_kernel<4><<<dim3(S / BM, 4), 256, 0, stream>>>(qb, kb, vtb, mask, Opart, lpart);
    combine_kernel<4><<<S, 256, 0, stream>>>(Opart, lpart, hb);
  }

  oproj_kernel<<<dim3(S / 64, 4), 256, 0, stream>>>(hb, Wob, bo, (float*)d_out);
}